// Round 13
// baseline (72.531 us; speedup 1.0000x reference)
//
#include <hip/hip_runtime.h>

#define B_ 32
#define N_ 4096
#define M_ 32
#define F_ 256
#define A_ 8

typedef float f32x4 __attribute__((ext_vector_type(4)));
typedef int   i32x4 __attribute__((ext_vector_type(4)));

// Single fused kernel, no workspace, no inter-block communication.
// e1 = h@(a1+a2) is provably irrelevant: e[b,n,k] = e1[b,n] + e2[b,k] and
// softmax over k is invariant to the per-row constant e1 (masked entries are
// -1e9 absolute; exp underflows to 0 either way; all-masked -> uniform 1/8).
// Each block redundantly computes its batch's anchor_feat (8x256) + e2 (8):
// 8x redundancy = 268 MFLOP total (~1.7us) -- cheaper than a graph-node
// boundary (~4-5us, measured R9) + separate anchor kernel (~2.5us).
#define ROWS_PER_BLOCK 512

__global__ __launch_bounds__(256) void fused_kernel(const float* __restrict__ fatoms,
                                                    const int* __restrict__ agraph,
                                                    const int* __restrict__ anchor_idx,
                                                    const float* __restrict__ W,
                                                    const float* __restrict__ a,
                                                    float* __restrict__ out) {
    int tid = threadIdx.x;
    int wv  = tid >> 6, ln = tid & 63;
    int b    = blockIdx.x >> 3;           // 256 blocks: b = bid/8
    int row0 = (blockIdx.x & 7) * ROWS_PER_BLOCK;

    __shared__ float xs[A_][F_];          // 8 KB: staged anchor atom rows
    __shared__ float paf[4][A_][F_];      // 32 KB: per-wave partial anchor_feat
    __shared__ float wred[4][A_];         // per-wave partial e2
    __shared__ float attn_s[ROWS_PER_BLOCK][A_];  // 16 KB

    // ---- anchor ids (uniform -> scalar regs) ----
    int anch[A_];
#pragma unroll
    for (int k = 0; k < A_; ++k) anch[k] = anchor_idx[b * A_ + k];

    // ---- issue agraph loads for this thread's 2 rows FIRST (hide under GEMM) ----
    const i32x4* gp0 = (const i32x4*)(agraph + ((size_t)b * N_ + row0 + tid) * M_);
    const i32x4* gp1 = (const i32x4*)(agraph + ((size_t)b * N_ + row0 + 256 + tid) * M_);
    i32x4 g0[M_ / 4], g1[M_ / 4];
#pragma unroll
    for (int j = 0; j < M_ / 4; ++j) g0[j] = gp0[j];
#pragma unroll
    for (int j = 0; j < M_ / 4; ++j) g1[j] = gp1[j];

    // ---- stage the 8 anchor atom rows (coalesced 1KB per row) ----
#pragma unroll
    for (int k = 0; k < A_; ++k)
        xs[k][tid] = fatoms[((size_t)b * N_ + anch[k]) * F_ + tid];
    __syncthreads();

    // ---- block-local anchor GEMM, K-split across waves ----
    // wave wv covers i in [64*wv, 64*wv+64); lane ln covers features [4ln,4ln+4)
    f32x4 acc[A_];
#pragma unroll
    for (int k = 0; k < A_; ++k) acc[k] = (f32x4){0.f, 0.f, 0.f, 0.f};
    {
        const float* wbase = W + (size_t)(wv * 64) * F_ + ln * 4;
        for (int i4 = 0; i4 < 64; i4 += 4) {
            f32x4 w0 = *(const f32x4*)(wbase + (size_t)(i4 + 0) * F_);
            f32x4 w1 = *(const f32x4*)(wbase + (size_t)(i4 + 1) * F_);
            f32x4 w2 = *(const f32x4*)(wbase + (size_t)(i4 + 2) * F_);
            f32x4 w3 = *(const f32x4*)(wbase + (size_t)(i4 + 3) * F_);
            int ib = wv * 64 + i4;
#pragma unroll
            for (int k = 0; k < A_; ++k) {
                f32x4 s = *(const f32x4*)&xs[k][ib];  // wave-uniform broadcast
                acc[k] += s.x * w0 + s.y * w1 + s.z * w2 + s.w * w3;
            }
        }
    }
    // partial e2 and partial anchor_feat -> LDS
    {
        f32x4 dd = *(const f32x4*)(a + ln * 4) - *(const f32x4*)(a + F_ + ln * 4);
#pragma unroll
        for (int k = 0; k < A_; ++k) {
            *(f32x4*)&paf[wv][k][ln * 4] = acc[k];
            float part = acc[k].x * dd.x + acc[k].y * dd.y +
                         acc[k].z * dd.z + acc[k].w * dd.w;
#pragma unroll
            for (int off = 32; off > 0; off >>= 1) part += __shfl_xor(part, off);
            if (ln == 0) wred[wv][k] = part;
        }
    }
    __syncthreads();

    // ---- E_k (uniform, computed redundantly per thread) ----
    float e2r[A_];
#pragma unroll
    for (int k = 0; k < A_; ++k)
        e2r[k] = (wred[0][k] + wred[1][k]) + (wred[2][k] + wred[3][k]);
    float m8 = e2r[0];
#pragma unroll
    for (int k = 1; k < A_; ++k) m8 = fmaxf(m8, e2r[k]);
    float E[A_];
#pragma unroll
    for (int k = 0; k < A_; ++k) E[k] = __expf(e2r[k] - m8);

    // ---- combine anchor_feat fragment for this lane ----
    f32x4 afr[A_];
#pragma unroll
    for (int k = 0; k < A_; ++k) {
        afr[k] = *(const f32x4*)&paf[0][k][ln * 4];
        afr[k] += *(const f32x4*)&paf[1][k][ln * 4];
        afr[k] += *(const f32x4*)&paf[2][k][ln * 4];
        afr[k] += *(const f32x4*)&paf[3][k][ln * 4];
    }

    // ---- mask + attn for this thread's 2 rows ----
#pragma unroll
    for (int half = 0; half < 2; ++half) {
        const i32x4* g = half ? g1 : g0;
        unsigned mk = 0;
#pragma unroll
        for (int j = 0; j < M_ / 4; ++j) {
#pragma unroll
            for (int k = 0; k < A_; ++k) {
                int hit = (g[j].x == anch[k]) | (g[j].y == anch[k]) |
                          (g[j].z == anch[k]) | (g[j].w == anch[k]);
                mk |= hit ? (1u << k) : 0u;
            }
        }
        float p[A_], s = 0.f;
#pragma unroll
        for (int k = 0; k < A_; ++k) { p[k] = (mk & (1u << k)) ? E[k] : 0.f; s += p[k]; }
        if (mk == 0) {  // all masked -> uniform
#pragma unroll
            for (int k = 0; k < A_; ++k) p[k] = 1.f;
            s = 8.f;
        }
        float rinv = __builtin_amdgcn_rcpf(s);
        int ridx = half * 256 + tid;
        f32x4 pa = {p[0] * rinv, p[1] * rinv, p[2] * rinv, p[3] * rinv};
        f32x4 pb = {p[4] * rinv, p[5] * rinv, p[6] * rinv, p[7] * rinv};
        *(f32x4*)&attn_s[ridx][0] = pa;
        *(f32x4*)&attn_s[ridx][4] = pb;
    }
    __syncthreads();

    // ---- streaming phase: wave wv writes rows [wv*128, wv*128+128) ----
    size_t base = ((size_t)b * N_ + row0 + wv * 128) * F_ + ln * 4;
    for (int r0 = 0; r0 < 128; r0 += 4) {
        f32x4 o[4];
#pragma unroll
        for (int u = 0; u < 4; ++u) {
            int r = wv * 128 + r0 + u;
            f32x4 pa = *(const f32x4*)&attn_s[r][0];  // broadcast reads
            f32x4 pb = *(const f32x4*)&attn_s[r][4];
            f32x4 t = pa.x * afr[0];
            t += pa.y * afr[1];
            t += pa.z * afr[2];
            t += pa.w * afr[3];
            t += pb.x * afr[4];
            t += pb.y * afr[5];
            t += pb.z * afr[6];
            t += pb.w * afr[7];
            o[u] = t;
        }
#pragma unroll
        for (int u = 0; u < 4; ++u)
            *(f32x4*)(out + base + (size_t)(r0 + u) * F_) = o[u];
    }
}

extern "C" void kernel_launch(void* const* d_in, const int* in_sizes, int n_in,
                              void* d_out, int out_size, void* d_ws, size_t ws_size,
                              hipStream_t stream) {
    const float* fatoms     = (const float*)d_in[0];
    const int*   agraph     = (const int*)d_in[1];
    const int*   anchor_idx = (const int*)d_in[2];
    const float* W          = (const float*)d_in[3];
    const float* a          = (const float*)d_in[4];
    float*       out        = (float*)d_out;

    hipLaunchKernelGGL(fused_kernel, dim3(B_ * (N_ / ROWS_PER_BLOCK)), dim3(256), 0,
                       stream, fatoms, agraph, anchor_idx, W, a, out);
}

// Round 14
// 51.885 us; speedup vs baseline: 1.3979x; 1.3979x over previous
//
#include <hip/hip_runtime.h>

#define B_ 32
#define N_ 4096
#define M_ 32
#define F_ 256
#define A_ 8

typedef float f32x4 __attribute__((ext_vector_type(4)));
typedef int   i32x4 __attribute__((ext_vector_type(4)));

// Single fused kernel, no workspace, no inter-block communication.
// e1 = h@(a1+a2) is provably irrelevant: e[b,n,k] = e1[b,n] + e2[b,k] and
// softmax over k is invariant to the per-row constant e1 (masked entries are
// -1e9 absolute; exp underflows to 0 either way; all-masked -> uniform 1/8).
// Each block redundantly computes its batch's anchor_feat + e2 block-locally
// (8x redundancy, K-split across waves, LDS-atomic combine): cheaper than a
// graph-node boundary (+4.9us measured R9) + separate anchor kernel (~2.5us).
// R13 lessons: LDS <= 25KB (alias xs inside attn_s), VGPR <= 128 (no spill).
#define ROWS_PER_BLOCK 512

__global__ __launch_bounds__(256, 4) void fused_kernel(const float* __restrict__ fatoms,
                                                       const int* __restrict__ agraph,
                                                       const int* __restrict__ anchor_idx,
                                                       const float* __restrict__ W,
                                                       const float* __restrict__ a,
                                                       float* __restrict__ out) {
    int tid = threadIdx.x;
    int wv  = tid >> 6, ln = tid & 63;
    int b    = blockIdx.x >> 3;            // 256 blocks: b = bid/8
    int row0 = (blockIdx.x & 7) * ROWS_PER_BLOCK;

    __shared__ float attn_s[ROWS_PER_BLOCK][A_];  // 16 KB; first 8KB aliased as xs
    __shared__ float af_s[A_][F_];                // 8 KB combined anchor_feat
    __shared__ float red_[4][A_];                 // per-wave partial e2
    float* xs_ = (float*)attn_s;                  // xs_[k*F_ + t], dead after GEMM

    // ---- anchor ids (uniform) ----
    int anch[A_];
#pragma unroll
    for (int k = 0; k < A_; ++k) anch[k] = anchor_idx[b * A_ + k];

    // ---- stage the 8 anchor atom rows into xs (coalesced 1KB/row); zero af_s ----
#pragma unroll
    for (int k = 0; k < A_; ++k)
        xs_[k * F_ + tid] = fatoms[((size_t)b * N_ + anch[k]) * F_ + tid];
#pragma unroll
    for (int k = 0; k < A_; ++k) af_s[k][tid] = 0.f;
    __syncthreads();

    // ---- block-local anchor GEMM, K-split across waves ----
    // wave wv covers i in [64wv, 64wv+64); lane ln covers features [4ln, 4ln+4)
    f32x4 acc[A_];
#pragma unroll
    for (int k = 0; k < A_; ++k) acc[k] = (f32x4){0.f, 0.f, 0.f, 0.f};
    {
        const float* wbase = W + (size_t)(wv * 64) * F_ + ln * 4;
        for (int i4 = 0; i4 < 64; i4 += 4) {
            f32x4 w0 = *(const f32x4*)(wbase + (size_t)(i4 + 0) * F_);
            f32x4 w1 = *(const f32x4*)(wbase + (size_t)(i4 + 1) * F_);
            f32x4 w2 = *(const f32x4*)(wbase + (size_t)(i4 + 2) * F_);
            f32x4 w3 = *(const f32x4*)(wbase + (size_t)(i4 + 3) * F_);
            int ib = wv * 64 + i4;
#pragma unroll
            for (int k = 0; k < A_; ++k) {
                f32x4 s = *(const f32x4*)&xs_[k * F_ + ib];  // uniform LDS broadcast
                acc[k] += s.x * w0 + s.y * w1 + s.z * w2 + s.w * w3;
            }
        }
    }
    __syncthreads();  // xs reads done (attn_s region free); af_s zeros visible

    // ---- combine partials: LDS atomic add into af_s ----
#pragma unroll
    for (int k = 0; k < A_; ++k) {
        float* ap = (float*)&acc[k];
#pragma unroll
        for (int j = 0; j < 4; ++j) atomicAdd(&af_s[k][ln * 4 + j], ap[j]);
    }

    // ---- issue this thread's 2 agraph rows now (latency hides under e2/E) ----
    const i32x4* gp0 = (const i32x4*)(agraph + ((size_t)b * N_ + row0 + tid) * M_);
    const i32x4* gp1 = (const i32x4*)(agraph + ((size_t)b * N_ + row0 + 256 + tid) * M_);
    i32x4 g0[M_ / 4], g1[M_ / 4];
#pragma unroll
    for (int j = 0; j < M_ / 4; ++j) g0[j] = gp0[j];
#pragma unroll
    for (int j = 0; j < M_ / 4; ++j) g1[j] = gp1[j];

    __syncthreads();  // af_s complete

    // ---- e2[k] = sum_f af_s[k][f] * (a1[f]-a2[f]) ----
    {
        float dd = a[tid] - a[tid + F_];
#pragma unroll
        for (int k = 0; k < A_; ++k) {
            float part = af_s[k][tid] * dd;
#pragma unroll
            for (int off = 32; off > 0; off >>= 1) part += __shfl_xor(part, off);
            if (ln == 0) red_[wv][k] = part;
        }
    }
    __syncthreads();

    // ---- E_k (uniform, redundant per thread) + afr fragments ----
    float E[A_];
    {
        float e2r[A_];
#pragma unroll
        for (int k = 0; k < A_; ++k)
            e2r[k] = (red_[0][k] + red_[1][k]) + (red_[2][k] + red_[3][k]);
        float m8 = e2r[0];
#pragma unroll
        for (int k = 1; k < A_; ++k) m8 = fmaxf(m8, e2r[k]);
#pragma unroll
        for (int k = 0; k < A_; ++k) E[k] = __expf(e2r[k] - m8);
    }
    f32x4 afr[A_];
#pragma unroll
    for (int k = 0; k < A_; ++k) afr[k] = *(const f32x4*)&af_s[k][ln * 4];

    // ---- mask + attn for this thread's 2 rows (attn_s reused; xs dead) ----
#pragma unroll
    for (int half = 0; half < 2; ++half) {
        const i32x4* g = half ? g1 : g0;
        unsigned mk = 0;
#pragma unroll
        for (int j = 0; j < M_ / 4; ++j) {
#pragma unroll
            for (int k = 0; k < A_; ++k) {
                int hit = (g[j].x == anch[k]) | (g[j].y == anch[k]) |
                          (g[j].z == anch[k]) | (g[j].w == anch[k]);
                mk |= hit ? (1u << k) : 0u;
            }
        }
        float p[A_], s = 0.f;
#pragma unroll
        for (int k = 0; k < A_; ++k) { p[k] = (mk & (1u << k)) ? E[k] : 0.f; s += p[k]; }
        if (mk == 0) {  // all masked -> uniform
#pragma unroll
            for (int k = 0; k < A_; ++k) p[k] = 1.f;
            s = 8.f;
        }
        float rinv = __builtin_amdgcn_rcpf(s);
        int ridx = half * 256 + tid;
        f32x4 pa = {p[0] * rinv, p[1] * rinv, p[2] * rinv, p[3] * rinv};
        f32x4 pb = {p[4] * rinv, p[5] * rinv, p[6] * rinv, p[7] * rinv};
        *(f32x4*)&attn_s[ridx][0] = pa;
        *(f32x4*)&attn_s[ridx][4] = pb;
    }
    __syncthreads();

    // ---- streaming phase: wave wv writes rows [wv*128, wv*128+128) ----
    size_t base = ((size_t)b * N_ + row0 + wv * 128) * F_ + ln * 4;
    for (int r0 = 0; r0 < 128; r0 += 4) {
        f32x4 o[4];
#pragma unroll
        for (int u = 0; u < 4; ++u) {
            int r = wv * 128 + r0 + u;
            f32x4 pa = *(const f32x4*)&attn_s[r][0];  // broadcast reads
            f32x4 pb = *(const f32x4*)&attn_s[r][4];
            f32x4 t = pa.x * afr[0];
            t += pa.y * afr[1];
            t += pa.z * afr[2];
            t += pa.w * afr[3];
            t += pb.x * afr[4];
            t += pb.y * afr[5];
            t += pb.z * afr[6];
            t += pb.w * afr[7];
            o[u] = t;
        }
#pragma unroll
        for (int u = 0; u < 4; ++u)
            *(f32x4*)(out + base + (size_t)(r0 + u) * F_) = o[u];
    }
}

extern "C" void kernel_launch(void* const* d_in, const int* in_sizes, int n_in,
                              void* d_out, int out_size, void* d_ws, size_t ws_size,
                              hipStream_t stream) {
    const float* fatoms     = (const float*)d_in[0];
    const int*   agraph     = (const int*)d_in[1];
    const int*   anchor_idx = (const int*)d_in[2];
    const float* W          = (const float*)d_in[3];
    const float* a          = (const float*)d_in[4];
    float*       out        = (float*)d_out;

    hipLaunchKernelGGL(fused_kernel, dim3(B_ * (N_ / ROWS_PER_BLOCK)), dim3(256), 0,
                       stream, fatoms, agraph, anchor_idx, W, a, out);
}

// Round 15
// 37.027 us; speedup vs baseline: 1.9589x; 1.4013x over previous
//
#include <hip/hip_runtime.h>

#define B_ 32
#define N_ 4096
#define M_ 32
#define F_ 256
#define A_ 8

typedef float f32x4 __attribute__((ext_vector_type(4)));
typedef int   i32x4 __attribute__((ext_vector_type(4)));

// workspace layout (floats):
//   [0, B*A*F)        anchor_feat (B,A,F)
//   [WS_E2, +B*A)     e2 = anchor_feat @ (a1-a2)
#define WS_AF 0
#define WS_E2 (B_ * A_ * F_)

// ---- kernel 1: anchor_feat[b,k,:] = fatoms[b, idx[b,k], :] @ W ; e2 ----
// e1 = h@(a1+a2) is provably irrelevant: e[b,n,k] = e1[b,n] + e2[b,k] and
// softmax over k is invariant to the per-row constant e1 (masked entries are
// -1e9 absolute; exp underflows to 0 either way; all-masked -> uniform 1/8).
__global__ __launch_bounds__(256) void anchor_kernel(const float* __restrict__ fatoms,
                                                     const int* __restrict__ anchor_idx,
                                                     const float* __restrict__ W,
                                                     const float* __restrict__ a,
                                                     float* __restrict__ ws) {
    int bk = blockIdx.x;  // b*A_ + k
    int b  = bk / A_;
    int f  = threadIdx.x;
    __shared__ float xs[F_];
    __shared__ float red[F_];
    int idx = anchor_idx[bk];
    xs[f] = fatoms[((size_t)b * N_ + idx) * F_ + f];
    __syncthreads();
    float acc[4] = {0.f, 0.f, 0.f, 0.f};
    for (int i0 = 0; i0 < F_; i0 += 16) {
#pragma unroll
        for (int j = 0; j < 16; ++j)
            acc[j & 3] += xs[i0 + j] * W[(i0 + j) * F_ + f];  // coalesced over f
    }
    float accs = (acc[0] + acc[1]) + (acc[2] + acc[3]);
    ws[WS_AF + bk * F_ + f] = accs;
    red[f] = accs * (a[f] - a[f + F_]);
    __syncthreads();
    for (int s = 128; s > 0; s >>= 1) {
        if (f < s) red[f] += red[f + s];
        __syncthreads();
    }
    if (f == 0) ws[WS_E2 + bk] = red[0];
}

// ---- kernel 2: main kernel — 1 wave per block, 64 rows ------------------
// ~94% of rows have NO anchor in their neighbor list (P(hit) ~ 8*32/4096):
// masked softmax degenerates to uniform 1/8 -> out row = afm (per-batch
// constant). Phase 2's common case is then a pure register store (fill-like),
// eliminating the ds_read + 32-FMA blend that capped the store stream.
#define RPW 64

__global__ __launch_bounds__(64) void main_kernel(const int* __restrict__ agraph,
                                                  const int* __restrict__ anchor_idx,
                                                  const float* __restrict__ ws,
                                                  float* __restrict__ out) {
    int lane = threadIdx.x;
    const int chunks_per_batch = N_ / RPW;  // 64
    int b     = blockIdx.x / chunks_per_batch;
    int chunk = blockIdx.x % chunks_per_batch;
    int row0  = chunk * RPW;

    // critical-path agraph loads first (row = row0+lane)
    const i32x4* gp = (const i32x4*)(agraph + ((size_t)b * N_ + row0 + lane) * M_);
    i32x4 g[M_ / 4];
#pragma unroll
    for (int j = 0; j < M_ / 4; ++j) g[j] = gp[j];

    const float* af = ws + WS_AF + b * (A_ * F_);
    const float* e2 = ws + WS_E2 + b * A_;

    __shared__ float attn[RPW][A_];
    __shared__ unsigned char flags[RPW];

    int   anch[A_];
    float e2r[A_];
#pragma unroll
    for (int k = 0; k < A_; ++k) {
        anch[k] = anchor_idx[b * A_ + k];
        e2r[k]  = e2[k];
    }
    // E_k = exp(e2_k - max_k e2)  (shared shift; masked-softmax ratios exact)
    float m8 = e2r[0];
#pragma unroll
    for (int k = 1; k < A_; ++k) m8 = fmaxf(m8, e2r[k]);
    float E[A_];
#pragma unroll
    for (int k = 0; k < A_; ++k) E[k] = __expf(e2r[k] - m8);

    f32x4 afr[A_];
#pragma unroll
    for (int k = 0; k < A_; ++k) afr[k] = *(const f32x4*)(af + k * F_ + lane * 4);
    // uniform-row constant: afm = (sum_k afr[k]) / 8   (rcp(8)=0.125 exact)
    f32x4 afm = ((afr[0] + afr[1]) + (afr[2] + afr[3])) +
                ((afr[4] + afr[5]) + (afr[6] + afr[7]));
    afm *= 0.125f;

    // ---- phase 1: one row per lane (all 64 lanes) ----
    {
        unsigned mk = 0;
#pragma unroll
        for (int j = 0; j < M_ / 4; ++j) {
#pragma unroll
            for (int k = 0; k < A_; ++k) {
                int hit = (g[j].x == anch[k]) | (g[j].y == anch[k]) |
                          (g[j].z == anch[k]) | (g[j].w == anch[k]);
                mk |= hit ? (1u << k) : 0u;
            }
        }
        flags[lane] = (unsigned char)(mk ? 1u : 0u);
        if (mk) {  // only non-uniform rows need stored weights (~6%)
            float p[A_], s = 0.f;
#pragma unroll
            for (int k = 0; k < A_; ++k) { p[k] = (mk & (1u << k)) ? E[k] : 0.f; s += p[k]; }
            float rinv = __builtin_amdgcn_rcpf(s);
            f32x4 pa = {p[0] * rinv, p[1] * rinv, p[2] * rinv, p[3] * rinv};
            f32x4 pb = {p[4] * rinv, p[5] * rinv, p[6] * rinv, p[7] * rinv};
            *(f32x4*)&attn[lane][0] = pa;
            *(f32x4*)&attn[lane][4] = pb;
        }
    }
    __syncthreads();  // single-wave block: cheap

    // ---- phase 2: wave writes its 64 rows (1KB/row) ----
    size_t base = ((size_t)b * N_ + row0) * F_ + lane * 4;
    for (int r0 = 0; r0 < RPW; r0 += 4) {
        unsigned f4 = *(const unsigned*)&flags[r0];  // 4 rows' flags, broadcast
        f32x4 o[4];
        if (f4 == 0) {  // fast path (~78% of groups): pure constant store
#pragma unroll
            for (int u = 0; u < 4; ++u) o[u] = afm;
        } else {
#pragma unroll
            for (int u = 0; u < 4; ++u) {
                if ((f4 >> (8 * u)) & 0xffu) {  // wave-uniform branch
                    f32x4 pa = *(const f32x4*)&attn[r0 + u][0];
                    f32x4 pb = *(const f32x4*)&attn[r0 + u][4];
                    f32x4 t = pa.x * afr[0];
                    t += pa.y * afr[1];
                    t += pa.z * afr[2];
                    t += pa.w * afr[3];
                    t += pb.x * afr[4];
                    t += pb.y * afr[5];
                    t += pb.z * afr[6];
                    t += pb.w * afr[7];
                    o[u] = t;
                } else {
                    o[u] = afm;
                }
            }
        }
#pragma unroll
        for (int u = 0; u < 4; ++u)
            *(f32x4*)(out + base + (size_t)(r0 + u) * F_) = o[u];
    }
}

extern "C" void kernel_launch(void* const* d_in, const int* in_sizes, int n_in,
                              void* d_out, int out_size, void* d_ws, size_t ws_size,
                              hipStream_t stream) {
    const float* fatoms     = (const float*)d_in[0];
    const int*   agraph     = (const int*)d_in[1];
    const int*   anchor_idx = (const int*)d_in[2];
    const float* W          = (const float*)d_in[3];
    const float* a          = (const float*)d_in[4];
    float*       out        = (float*)d_out;
    float*       ws         = (float*)d_ws;

    hipLaunchKernelGGL(anchor_kernel, dim3(B_ * A_), dim3(256), 0, stream,
                       fatoms, anchor_idx, W, a, ws);
    hipLaunchKernelGGL(main_kernel, dim3(B_ * (N_ / RPW)), dim3(64), 0, stream,
                       agraph, anchor_idx, ws, out);
}

// Round 16
// 35.855 us; speedup vs baseline: 2.0229x; 1.0327x over previous
//
#include <hip/hip_runtime.h>

#define B_ 32
#define N_ 4096
#define M_ 32
#define F_ 256
#define A_ 8

typedef float f32x4 __attribute__((ext_vector_type(4)));
typedef int   i32x4 __attribute__((ext_vector_type(4)));

// workspace layout:
//   floats [0, B*A*F)        anchor_feat (B,A,F)
//   floats [WS_E2, +B*A)     e2 = anchor_feat @ (a1-a2)
//   bytes  at WS_FLAGS_F     per-row 8-bit anchor-hit mask (B*N bytes)
#define WS_AF 0
#define WS_E2 (B_ * A_ * F_)
#define WS_FLAGS_F (WS_E2 + B_ * A_)

// ---- kernel 1 (node 1): anchor GEMM blocks || agraph mask-scan blocks ----
// Independent block ranges, no cross-block communication (R10/R11 lesson).
// e1 = h@(a1+a2) is provably irrelevant: e[b,n,k] = e1[b,n] + e2[b,k] and
// softmax over k is invariant to the per-row constant e1 (masked entries are
// -1e9 absolute; exp underflows to 0 either way; all-masked -> uniform 1/8).
#define MASK_BLOCKS (B_ * N_ / 256)  // 512

__global__ __launch_bounds__(256) void prep_kernel(const float* __restrict__ fatoms,
                                                   const int* __restrict__ agraph,
                                                   const int* __restrict__ anchor_idx,
                                                   const float* __restrict__ W,
                                                   const float* __restrict__ a,
                                                   float* __restrict__ ws,
                                                   unsigned char* __restrict__ flags) {
    int tid = threadIdx.x;

    if (blockIdx.x < (unsigned)(B_ * A_)) {
        // ---- anchor part: anchor_feat[bk] + e2[bk] (R15 anchor body) ----
        int bk = blockIdx.x;
        int b  = bk / A_;
        __shared__ float xs[F_];
        __shared__ float red[F_];
        int idx = anchor_idx[bk];
        xs[tid] = fatoms[((size_t)b * N_ + idx) * F_ + tid];
        __syncthreads();
        float acc[4] = {0.f, 0.f, 0.f, 0.f};
        for (int i0 = 0; i0 < F_; i0 += 16) {
#pragma unroll
            for (int j = 0; j < 16; ++j)
                acc[j & 3] += xs[i0 + j] * W[(i0 + j) * F_ + tid];  // coalesced
        }
        float accs = (acc[0] + acc[1]) + (acc[2] + acc[3]);
        ws[WS_AF + bk * F_ + tid] = accs;
        red[tid] = accs * (a[tid] - a[tid + F_]);
        __syncthreads();
        for (int s = 128; s > 0; s >>= 1) {
            if (tid < s) red[tid] += red[tid + s];
            __syncthreads();
        }
        if (tid == 0) ws[WS_E2 + bk] = red[0];
    } else {
        // ---- mask part: one row per thread; write 8-bit hit mask ----
        int mb   = blockIdx.x - B_ * A_;   // 0..511
        int b    = mb >> 4;                // 16 blocks per batch
        int gidx = mb * 256 + tid;         // == b*N + row (rows in order)

        int anch[A_];
#pragma unroll
        for (int k = 0; k < A_; ++k) anch[k] = anchor_idx[b * A_ + k];

        const i32x4* gp = (const i32x4*)(agraph + (size_t)gidx * M_);
        i32x4 g[M_ / 4];
#pragma unroll
        for (int j = 0; j < M_ / 4; ++j) g[j] = gp[j];

        unsigned mk = 0;
#pragma unroll
        for (int j = 0; j < M_ / 4; ++j) {
#pragma unroll
            for (int k = 0; k < A_; ++k) {
                int hit = (g[j].x == anch[k]) | (g[j].y == anch[k]) |
                          (g[j].z == anch[k]) | (g[j].w == anch[k]);
                mk |= hit ? (1u << k) : 0u;
            }
        }
        flags[gidx] = (unsigned char)mk;
    }
}

// ---- kernel 2 (node 2): fill-like streaming store, no LDS, no barrier ----
__global__ __launch_bounds__(64) void stream_kernel(const float* __restrict__ ws,
                                                    const unsigned char* __restrict__ flags,
                                                    float* __restrict__ out) {
    int lane = threadIdx.x;
    int b    = blockIdx.x >> 6;
    int row0 = (int)(blockIdx.x & 63) * 64;

    const float* af = ws + WS_AF + b * (A_ * F_);
    f32x4 afr[A_];
#pragma unroll
    for (int k = 0; k < A_; ++k) afr[k] = *(const f32x4*)(af + k * F_ + lane * 4);

    float e2r[A_];
#pragma unroll
    for (int k = 0; k < A_; ++k) e2r[k] = ws[WS_E2 + b * A_ + k];
    float m8 = e2r[0];
#pragma unroll
    for (int k = 1; k < A_; ++k) m8 = fmaxf(m8, e2r[k]);
    float E[A_];
#pragma unroll
    for (int k = 0; k < A_; ++k) E[k] = __expf(e2r[k] - m8);

    // uniform-row constant: afm = (sum_k afr[k]) / 8  (exact)
    f32x4 afm = ((afr[0] + afr[1]) + (afr[2] + afr[3])) +
                ((afr[4] + afr[5]) + (afr[6] + afr[7]));
    afm *= 0.125f;

    const unsigned* fb = (const unsigned*)(flags + (size_t)b * N_ + row0);
    size_t base = ((size_t)b * N_ + row0) * F_ + lane * 4;

    for (int r0 = 0; r0 < 64; r0 += 4) {
        unsigned f4 = fb[r0 >> 2];  // wave-uniform -> scalar load + s_cbranch
        f32x4 o[4];
        if (f4 == 0) {  // ~78% of groups: pure constant store
#pragma unroll
            for (int u = 0; u < 4; ++u) o[u] = afm;
        } else {
#pragma unroll
            for (int u = 0; u < 4; ++u) {
                unsigned mku = (f4 >> (8 * u)) & 0xffu;
                if (mku) {
                    float p[A_], s = 0.f;
#pragma unroll
                    for (int k = 0; k < A_; ++k) {
                        p[k] = (mku & (1u << k)) ? E[k] : 0.f;
                        s += p[k];
                    }
                    float rinv = __builtin_amdgcn_rcpf(s);
                    f32x4 t = (p[0] * rinv) * afr[0];
                    t += (p[1] * rinv) * afr[1];
                    t += (p[2] * rinv) * afr[2];
                    t += (p[3] * rinv) * afr[3];
                    t += (p[4] * rinv) * afr[4];
                    t += (p[5] * rinv) * afr[5];
                    t += (p[6] * rinv) * afr[6];
                    t += (p[7] * rinv) * afr[7];
                    o[u] = t;
                } else {
                    o[u] = afm;
                }
            }
        }
#pragma unroll
        for (int u = 0; u < 4; ++u)
            *(f32x4*)(out + base + (size_t)(r0 + u) * F_) = o[u];
    }
}

extern "C" void kernel_launch(void* const* d_in, const int* in_sizes, int n_in,
                              void* d_out, int out_size, void* d_ws, size_t ws_size,
                              hipStream_t stream) {
    const float* fatoms     = (const float*)d_in[0];
    const int*   agraph     = (const int*)d_in[1];
    const int*   anchor_idx = (const int*)d_in[2];
    const float* W          = (const float*)d_in[3];
    const float* a          = (const float*)d_in[4];
    float*       out        = (float*)d_out;
    float*       ws         = (float*)d_ws;
    unsigned char* flags    = (unsigned char*)(ws + WS_FLAGS_F);

    hipLaunchKernelGGL(prep_kernel, dim3(B_ * A_ + MASK_BLOCKS), dim3(256), 0, stream,
                       fatoms, agraph, anchor_idx, W, a, ws, flags);
    hipLaunchKernelGGL(stream_kernel, dim3(B_ * (N_ / 64)), dim3(64), 0, stream,
                       ws, flags, out);
}

// Round 17
// 35.419 us; speedup vs baseline: 2.0478x; 1.0123x over previous
//
#include <hip/hip_runtime.h>

#define B_ 32
#define N_ 4096
#define M_ 32
#define F_ 256
#define A_ 8

typedef float f32x4 __attribute__((ext_vector_type(4)));
typedef int   i32x4 __attribute__((ext_vector_type(4)));

// workspace layout:
//   floats [0, B*A*F)        anchor_feat (B,A,F)
//   floats [WS_E2, +B*A)     e2 = anchor_feat @ (a1-a2)
//   bytes  at WS_FLAGS_F     per-row 8-bit anchor-hit mask (B*N bytes)
#define WS_AF 0
#define WS_E2 (B_ * A_ * F_)
#define WS_FLAGS_F (WS_E2 + B_ * A_)

// ---- kernel 1 (node 1): anchor GEMM blocks || agraph mask-scan blocks ----
// Independent block ranges, no cross-block communication (R10/R11 lesson).
// e1 = h@(a1+a2) is provably irrelevant: e[b,n,k] = e1[b,n] + e2[b,k] and
// softmax over k is invariant to the per-row constant e1 (masked entries are
// -1e9 absolute; exp underflows to 0 either way; all-masked -> uniform 1/8).
#define MASK_BLOCKS (B_ * N_ / 256)  // 512

__global__ __launch_bounds__(256) void prep_kernel(const float* __restrict__ fatoms,
                                                   const int* __restrict__ agraph,
                                                   const int* __restrict__ anchor_idx,
                                                   const float* __restrict__ W,
                                                   const float* __restrict__ a,
                                                   float* __restrict__ ws,
                                                   unsigned char* __restrict__ flags) {
    int tid = threadIdx.x;

    if (blockIdx.x < (unsigned)(B_ * A_)) {
        // ---- anchor part: anchor_feat[bk] + e2[bk] ----
        int bk = blockIdx.x;
        int b  = bk / A_;
        __shared__ float xs[F_];
        __shared__ float red[F_];
        int idx = anchor_idx[bk];
        xs[tid] = fatoms[((size_t)b * N_ + idx) * F_ + tid];
        __syncthreads();
        float acc[4] = {0.f, 0.f, 0.f, 0.f};
        for (int i0 = 0; i0 < F_; i0 += 16) {
#pragma unroll
            for (int j = 0; j < 16; ++j)
                acc[j & 3] += xs[i0 + j] * W[(i0 + j) * F_ + tid];  // coalesced
        }
        float accs = (acc[0] + acc[1]) + (acc[2] + acc[3]);
        ws[WS_AF + bk * F_ + tid] = accs;
        red[tid] = accs * (a[tid] - a[tid + F_]);
        __syncthreads();
        for (int s = 128; s > 0; s >>= 1) {
            if (tid < s) red[tid] += red[tid + s];
            __syncthreads();
        }
        if (tid == 0) ws[WS_E2 + bk] = red[0];
    } else {
        // ---- mask part: one row per thread; write 8-bit hit mask ----
        int mb   = blockIdx.x - B_ * A_;   // 0..511
        int b    = mb >> 4;                // 16 blocks per batch
        int gidx = mb * 256 + tid;         // == b*N + row (rows in order)

        int anch[A_];
#pragma unroll
        for (int k = 0; k < A_; ++k) anch[k] = anchor_idx[b * A_ + k];

        const i32x4* gp = (const i32x4*)(agraph + (size_t)gidx * M_);
        i32x4 g[M_ / 4];
#pragma unroll
        for (int j = 0; j < M_ / 4; ++j) g[j] = gp[j];

        unsigned mk = 0;
#pragma unroll
        for (int j = 0; j < M_ / 4; ++j) {
#pragma unroll
            for (int k = 0; k < A_; ++k) {
                int hit = (g[j].x == anch[k]) | (g[j].y == anch[k]) |
                          (g[j].z == anch[k]) | (g[j].w == anch[k]);
                mk |= hit ? (1u << k) : 0u;
            }
        }
        flags[gidx] = (unsigned char)mk;
    }
}

// ---- kernel 2 (node 2): fill-like streaming store ----------------------
// Fill-kernel geometry: 512 blocks x 256 threads (4 waves); wave w owns 64
// consecutive rows. All 16 flag dwords preloaded via scalar loads up front
// (no load->branch->store serialization).
__global__ __launch_bounds__(256) void stream_kernel(const float* __restrict__ ws,
                                                     const unsigned char* __restrict__ flags,
                                                     float* __restrict__ out) {
    int tid  = threadIdx.x;
    int w    = __builtin_amdgcn_readfirstlane(tid >> 6);  // wave id -> SGPR
    int lane = tid & 63;
    int b    = blockIdx.x >> 4;                    // 512 blocks: 16 per batch
    int row0 = ((int)(blockIdx.x & 15) * 4 + w) * 64;

    const float* af = ws + WS_AF + b * (A_ * F_);
    f32x4 afr[A_];
#pragma unroll
    for (int k = 0; k < A_; ++k) afr[k] = *(const f32x4*)(af + k * F_ + lane * 4);

    float e2r[A_];
#pragma unroll
    for (int k = 0; k < A_; ++k) e2r[k] = ws[WS_E2 + b * A_ + k];
    float m8 = e2r[0];
#pragma unroll
    for (int k = 1; k < A_; ++k) m8 = fmaxf(m8, e2r[k]);
    float E[A_];
#pragma unroll
    for (int k = 0; k < A_; ++k) E[k] = __expf(e2r[k] - m8);

    // uniform-row constant: afm = (sum_k afr[k]) / 8  (exact)
    f32x4 afm = ((afr[0] + afr[1]) + (afr[2] + afr[3])) +
                ((afr[4] + afr[5]) + (afr[6] + afr[7]));
    afm *= 0.125f;

    // preload all 16 flag dwords for this wave's 64 rows (scalar burst)
    const unsigned* fb = (const unsigned*)(flags + (size_t)b * N_ + row0);
    unsigned f16[16];
#pragma unroll
    for (int j = 0; j < 16; ++j) f16[j] = fb[j];

    size_t base = ((size_t)b * N_ + row0) * F_ + lane * 4;
    for (int r0 = 0; r0 < 64; r0 += 4) {
        unsigned f4 = f16[r0 >> 2];
        f32x4 o[4];
        if (f4 == 0) {  // ~78% of groups: pure constant store
#pragma unroll
            for (int u = 0; u < 4; ++u) o[u] = afm;
        } else {
#pragma unroll
            for (int u = 0; u < 4; ++u) {
                unsigned mku = (f4 >> (8 * u)) & 0xffu;
                if (mku) {
                    float p[A_], s = 0.f;
#pragma unroll
                    for (int k = 0; k < A_; ++k) {
                        p[k] = (mku & (1u << k)) ? E[k] : 0.f;
                        s += p[k];
                    }
                    float rinv = __builtin_amdgcn_rcpf(s);
                    f32x4 t = (p[0] * rinv) * afr[0];
                    t += (p[1] * rinv) * afr[1];
                    t += (p[2] * rinv) * afr[2];
                    t += (p[3] * rinv) * afr[3];
                    t += (p[4] * rinv) * afr[4];
                    t += (p[5] * rinv) * afr[5];
                    t += (p[6] * rinv) * afr[6];
                    t += (p[7] * rinv) * afr[7];
                    o[u] = t;
                } else {
                    o[u] = afm;
                }
            }
        }
#pragma unroll
        for (int u = 0; u < 4; ++u)
            *(f32x4*)(out + base + (size_t)(r0 + u) * F_) = o[u];
    }
}

extern "C" void kernel_launch(void* const* d_in, const int* in_sizes, int n_in,
                              void* d_out, int out_size, void* d_ws, size_t ws_size,
                              hipStream_t stream) {
    const float* fatoms     = (const float*)d_in[0];
    const int*   agraph     = (const int*)d_in[1];
    const int*   anchor_idx = (const int*)d_in[2];
    const float* W          = (const float*)d_in[3];
    const float* a          = (const float*)d_in[4];
    float*       out        = (float*)d_out;
    float*       ws         = (float*)d_ws;
    unsigned char* flags    = (unsigned char*)(ws + WS_FLAGS_F);

    hipLaunchKernelGGL(prep_kernel, dim3(B_ * A_ + MASK_BLOCKS), dim3(256), 0, stream,
                       fatoms, agraph, anchor_idx, W, a, ws, flags);
    hipLaunchKernelGGL(stream_kernel, dim3(B_ * (N_ / 256)), dim3(256), 0, stream,
                       ws, flags, out);
}